// Round 5
// baseline (165.605 us; speedup 1.0000x reference)
//
#include <hip/hip_runtime.h>
#include <hip/hip_bf16.h>

typedef short short8 __attribute__((ext_vector_type(8)));
typedef short short4_t __attribute__((ext_vector_type(4)));
typedef float floatx4 __attribute__((ext_vector_type(4)));

#define DEVI __device__ __forceinline__

// Dims: B=4, T=4096, D=256, E=12 (4x k5, 4x k9, 4x k17), 16384 tokens.
// fp32 in/out; MFMA operands bf16.
//
// R5: LDS-instruction-count reduction (R4 analysis: LDS pipe ~4.2k cy of the
//   8.4k cy/chunk; MFMA 310, VALU 1.2k).
//   - conv x-window lives in REGISTERS (32 packed uint/thread, loaded from xs
//     once) -> zero per-chunk conv LDS reads (was ~1200 cy/chunk).
//   - conv handles 2 packed d-channels/thread, writes b32 (halved writes).
//   - full-expert chunks (K=256): 12 chunks, As[64][264] aliases the dead xs
//     region -> barriers halve. B dbuf = same 64 VGPR (BA=d0..127,BB=d128..255).
//   - wts_s relayout [12][64] -> 4 float4 reads/chunk instead of 16 scalar.
//   - out-projection B prefetched into freed BA/BB during LN phase.
//   Register budget ~215 peak < 256 cap (launch_bounds(512,1), 8 waves/CU).
//
// ws: projWT bf16 [12][256f][256d] @ 0         (1,572,864)
//     outWT  bf16 [256f][256k]     @ 1,572,864 (131,072)
//     projbT bf16 [256n][32k]      @ 1,703,936 (16,384)  (k>=12 zero)
//     rWT    bf16 [16e][256d]      @ 1,720,320 (8,192)   (e>=12 zero)

DEVI float bf2f(__hip_bfloat16 v) { return __bfloat162float(v); }
DEVI __hip_bfloat16 f2bf(float v) { return __float2bfloat16(v); }
DEVI unsigned short bfbits(float v) { __hip_bfloat16 b = f2bf(v); return *(unsigned short*)&b; }

// ---------------------------------------------------------------- prep ----
// 209 blocks: 0..191 projW 64x64 transpose tiles, 192..207 outW, 208 misc.
__global__ __launch_bounds__(256) void prep_kernel(
    const float* __restrict__ rW,      // [256][12]
    const float* __restrict__ projW,   // [12][256d][256f]
    const float* __restrict__ outW,    // [256k][256f]
    const float* __restrict__ projb,   // [12][256]
    __hip_bfloat16* __restrict__ projWT,
    __hip_bfloat16* __restrict__ outWT,
    __hip_bfloat16* __restrict__ projbT,
    __hip_bfloat16* __restrict__ rWT)
{
    __shared__ __align__(16) __hip_bfloat16 Tt[64 * 72];
    const int bid = blockIdx.x;
    const int tid = threadIdx.x;

    if (bid == 208) {
#pragma unroll
        for (int k = 0; k < 32; k++)
            projbT[tid * 32 + k] = (k < 12) ? f2bf(projb[k * 256 + tid]) : f2bf(0.f);
#pragma unroll
        for (int e = 0; e < 16; e++)
            rWT[e * 256 + tid] = (e < 12) ? f2bf(rW[tid * 12 + e]) : f2bf(0.f);
        return;
    }
    const float* src;
    __hip_bfloat16* dst;
    if (bid < 192) {
        int e = bid >> 4, ti = (bid & 15) >> 2, tj = bid & 3;
        src = projW + (e << 16) + (ti * 64) * 256 + tj * 64;
        dst = projWT + (e << 16) + (tj * 64) * 256 + ti * 64;
    } else {
        int b3 = bid - 192, ti = b3 >> 2, tj = b3 & 3;
        src = outW + (ti * 64) * 256 + tj * 64;
        dst = outWT + (tj * 64) * 256 + ti * 64;
    }
#pragma unroll
    for (int i = 0; i < 4; i++) {
        int r = i * 16 + (tid >> 4);
        int c4 = (tid & 15) * 4;
        float4 f = *(const float4*)(src + r * 256 + c4);
        Tt[(c4 + 0) * 72 + r] = f2bf(f.x);
        Tt[(c4 + 1) * 72 + r] = f2bf(f.y);
        Tt[(c4 + 2) * 72 + r] = f2bf(f.z);
        Tt[(c4 + 3) * 72 + r] = f2bf(f.w);
    }
    __syncthreads();
#pragma unroll
    for (int i = 0; i < 2; i++) {
        int c = i * 32 + (tid >> 3);
        int r8 = (tid & 7) * 8;
        *(short8*)(dst + c * 256 + r8) = *(const short8*)(Tt + c * 72 + r8);
    }
}

// --------------------------------------------------------------- fused ----
// LDS map (50,432 B static, 1 block/CU):
//   xs    bf16 [80][264] @ 0       (42,240)  x tile incl. 16-row causal halo
//     (after window+router reads, first 33,792 B reused as:)
//   As    bf16 [64][264] @ 0       (33,792)  full-expert A chunk / later normed
//   wts_s f32  [12][64]  @ 42,240  ( 3,072)  router weights, expert-major
//   psum  f32  [64][9]   @ 45,312  ( 2,304)
//   psq   f32  [64][9]   @ 47,616  ( 2,304)
//   muA   f32  [64]      @ 49,920  rsA f32 [64] @ 50,176

// conv over register window: 16 t-rows x 2 packed d-channels per thread.
template<int K>
DEVI void conv_reg(const float2 (&cf)[17], const unsigned (&xr)[32],
                   const float4 (&wt4)[4], unsigned* __restrict__ dp)
{
    constexpr int OFF = 17 - K;
#pragma unroll
    for (int t = 0; t < 16; t++) {
        float y0 = 0.f, y1 = 0.f;
#pragma unroll
        for (int i = 0; i < K; i++) {
            unsigned u = xr[t + OFF + i];
            y0 = fmaf(cf[i].x, __uint_as_float(u << 16), y0);
            y1 = fmaf(cf[i].y, __uint_as_float(u & 0xffff0000u), y1);
        }
        float wt = wt4[t >> 2][t & 3];
        unsigned pv = ((unsigned)bfbits(y1 * wt) << 16) | (unsigned)bfbits(y0 * wt);
        dp[t * 132] = pv;                 // As stride 264 bf16 = 132 uint
    }
}

// GEMM with register-preloaded B: M=64 (4 m-frags) x N=32 (2 nt) x K=NKS*32.
template<int NKS>
DEVI void gemm_pre(const __hip_bfloat16* __restrict__ A, int astride,
                   const short8 (&B)[4][2], floatx4 (&acc)[4][2],
                   int l16, int quad)
{
    const __hip_bfloat16* ap = A + l16 * astride + quad * 8;
    short8 a[4];
#pragma unroll
    for (int mf = 0; mf < 4; mf++) a[mf] = *(const short8*)(ap + mf * 16 * astride);
#pragma unroll
    for (int ks = 0; ks < NKS; ks++) {
        short8 na[4];
        if (ks < NKS - 1) {
#pragma unroll
            for (int mf = 0; mf < 4; mf++)
                na[mf] = *(const short8*)(ap + mf * 16 * astride + (ks + 1) * 32);
        }
#pragma unroll
        for (int nt = 0; nt < 2; nt++)
#pragma unroll
            for (int mf = 0; mf < 4; mf++)
                acc[mf][nt] = __builtin_amdgcn_mfma_f32_16x16x32_bf16(
                    a[mf], B[ks][nt], acc[mf][nt], 0, 0, 0);
        if (ks < NKS - 1) {
#pragma unroll
            for (int mf = 0; mf < 4; mf++) a[mf] = na[mf];
        }
    }
}

__global__ __launch_bounds__(512, 1) void fused_kernel(
    const float* __restrict__ x,
    const float* __restrict__ ck5, const float* __restrict__ ck9,
    const float* __restrict__ ck17,
    const float* __restrict__ rb,      // [12]
    const float* __restrict__ gmm, const float* __restrict__ bta,
    const float* __restrict__ outb,
    const __hip_bfloat16* __restrict__ projWT,
    const __hip_bfloat16* __restrict__ outWT,
    const __hip_bfloat16* __restrict__ projbT,
    const __hip_bfloat16* __restrict__ rWT,
    float* __restrict__ out)
{
    __shared__ __align__(16) char smem[50432];
    __hip_bfloat16* xs = (__hip_bfloat16*)smem;            // [80][264]
    __hip_bfloat16* As = (__hip_bfloat16*)smem;            // [64][264] (aliases xs)
    __hip_bfloat16* normed = (__hip_bfloat16*)smem;        // [64][264] (later)
    float* wts_s = (float*)(smem + 42240);                 // [12][64]
    float* psum  = (float*)(smem + 45312);                 // [64][9]
    float* psq   = (float*)(smem + 47616);                 // [64][9]
    float* muA   = (float*)(smem + 49920);
    float* rsA   = (float*)(smem + 50176);

    const int tid  = threadIdx.x;
    const int wave = tid >> 6;                 // 0..7
    const int lane = tid & 63;
    const int quad = lane >> 4;
    const int l16  = lane & 15;
    const int nsl  = wave * 32;                // 32-wide f-slice per wave
    const int m0   = blockIdx.x * 64;
    const int bb   = m0 >> 12;
    const int t0   = m0 & 4095;

    // ---- stage x tile rows t0-16..t0+63, fp32 -> bf16 ----
    {
        const float* xb = x + (size_t)bb * 4096 * 256;
        for (int idx = tid; idx < 80 * 64; idx += 512) {
            int row = idx >> 6, c4 = (idx & 63) << 2;
            int gt = t0 - 16 + row;
            short4_t v = {0, 0, 0, 0};
            if (gt >= 0) {
                float4 f = *(const float4*)(xb + (size_t)gt * 256 + c4);
                v[0] = (short)bfbits(f.x); v[1] = (short)bfbits(f.y);
                v[2] = (short)bfbits(f.z); v[3] = (short)bfbits(f.w);
            }
            *(short4_t*)(xs + row * 264 + c4) = v;
        }
    }
    __syncthreads();

    // ---- router (waves 0..3): MFMA logits + shuffle softmax -> wts_s[12][64]
    if (wave < 4) {
        floatx4 ra = {0.f, 0.f, 0.f, 0.f};
        const __hip_bfloat16* ap = xs + (16 + wave * 16 + l16) * 264 + quad * 8;
        const __hip_bfloat16* bp = rWT + l16 * 256 + quad * 8;
#pragma unroll
        for (int kk = 0; kk < 256; kk += 32)
            ra = __builtin_amdgcn_mfma_f32_16x16x32_bf16(
                *(const short8*)(ap + kk), *(const short8*)(bp + kk), ra, 0, 0, 0);
        float rbv = (l16 < 12) ? rb[l16] : 0.f;
#pragma unroll
        for (int r = 0; r < 4; r++) {
            float v = (l16 < 12) ? (ra[r] + rbv) : -1e30f;
            float mx = v;
            mx = fmaxf(mx, __shfl_xor(mx, 1));
            mx = fmaxf(mx, __shfl_xor(mx, 2));
            mx = fmaxf(mx, __shfl_xor(mx, 4));
            mx = fmaxf(mx, __shfl_xor(mx, 8));
            float ex = (l16 < 12) ? __expf(v - mx) : 0.f;
            float sm = ex;
            sm += __shfl_xor(sm, 1);
            sm += __shfl_xor(sm, 2);
            sm += __shfl_xor(sm, 4);
            sm += __shfl_xor(sm, 8);
            if (l16 < 12) wts_s[l16 * 64 + (wave * 16 + quad * 4 + r)] = ex / sm;
        }
    }

    // ---- conv x-window into registers (read xs ONCE) ----
    // thread owns d-channels (d0, d0+1), t-rows tloc..tloc+15.
    const int d0   = 2 * (tid & 127);          // 0..254
    const int tloc = (tid >> 7) * 16;          // 0/16/32/48
    unsigned xr[32];
#pragma unroll
    for (int j = 0; j < 32; j++)
        xr[j] = *(const unsigned*)(xs + (tloc + j) * 264 + d0);
    __syncthreads();                           // xs fully read; wts_s ready

    // ---- helpers -------------------------------------------------------
    auto loadCoef = [&](float2 (&cf)[17], int e) {
        if (e < 4) {
            const float* cw = ck5 + e * 5 * 256;
#pragma unroll
            for (int j = 0; j < 17; j++)
                cf[j] = (j < 5) ? *(const float2*)(cw + j * 256 + d0) : make_float2(0.f, 0.f);
        } else if (e < 8) {
            const float* cw = ck9 + (e - 4) * 9 * 256;
#pragma unroll
            for (int j = 0; j < 17; j++)
                cf[j] = (j < 9) ? *(const float2*)(cw + j * 256 + d0) : make_float2(0.f, 0.f);
        } else {
            const float* cw = ck17 + (e - 8) * 17 * 256;
#pragma unroll
            for (int j = 0; j < 17; j++)
                cf[j] = *(const float2*)(cw + j * 256 + d0);
        }
    };
    auto loadB8 = [&](short8 (&B)[4][2], const __hip_bfloat16* base, int rs, int kstep) {
#pragma unroll
        for (int ks = 0; ks < 4; ks++)
#pragma unroll
            for (int nt = 0; nt < 2; nt++)
                B[ks][nt] = *(const short8*)(base + nt * 16 * rs + ks * kstep);
    };
    auto produce = [&](int e, const float2 (&cf)[17]) {
        float4 wt4[4];
#pragma unroll
        for (int g = 0; g < 4; g++)
            wt4[g] = *(const float4*)(wts_s + e * 64 + tloc + 4 * g);
        unsigned* dp = (unsigned*)As + tloc * 132 + (d0 >> 1);
        if (e < 4)      conv_reg<5>(cf, xr, wt4, dp);
        else if (e < 8) conv_reg<9>(cf, xr, wt4, dp);
        else            conv_reg<17>(cf, xr, wt4, dp);
    };
    auto produceBias = [&]() {
        int t = tid >> 3, k4 = (tid & 7) * 4;
        short4_t v;
#pragma unroll
        for (int j = 0; j < 4; j++) {
            int k = k4 + j;
            v[j] = (k < 12) ? (short)bfbits(wts_s[k * 64 + t]) : (short)0;
        }
        *(short4_t*)(As + t * 264 + k4) = v;
    };

    floatx4 acc[4][2];
#pragma unroll
    for (int i = 0; i < 4; i++)
#pragma unroll
        for (int j = 0; j < 2; j++) acc[i][j] = {0.f, 0.f, 0.f, 0.f};

    float2 cf[17];
    short8 BA[4][2], BB[4][2];

    // prologue: expert 0
    loadCoef(cf, 0);
    loadB8(BA, projWT + (0 << 16) + 0   + (nsl + l16) * 256 + quad * 8, 256, 32);
    loadB8(BB, projWT + (0 << 16) + 128 + (nsl + l16) * 256 + quad * 8, 256, 32);
    produce(0, cf);
    __syncthreads();

    // 12 full-expert chunks (K=256 each) + bias chunk.
#pragma unroll 1
    for (int c = 0; c < 12; c++) {
        if (c < 11) loadCoef(cf, c + 1);       // single-buffer: produce(c) done
        gemm_pre<4>(As, 264, BA, acc, l16, quad);        // d 0..127
        gemm_pre<4>(As + 128, 264, BB, acc, l16, quad);  // d 128..255
        if (c < 11) {
            int e = c + 1;
            loadB8(BA, projWT + (e << 16) + 0   + (nsl + l16) * 256 + quad * 8, 256, 32);
            loadB8(BB, projWT + (e << 16) + 128 + (nsl + l16) * 256 + quad * 8, 256, 32);
        } else {
            loadB8(BA, projbT + (nsl + l16) * 32 + quad * 8, 32, 0);  // bias B
        }
        __syncthreads();                       // As consumed by all waves
        if (c < 11) produce(c + 1, cf);
        else        produceBias();
        __syncthreads();                       // As ready
    }
    // bias chunk: A = router wts [64][32], B = projbT
    gemm_pre<1>(As, 264, BA, acc, l16, quad);

    // out-projection B prefetch into freed BA/BB (covered by LN phase)
    loadB8(BA, outWT + 0   + (nsl + l16) * 256 + quad * 8, 256, 32);
    loadB8(BB, outWT + 128 + (nsl + l16) * 256 + quad * 8, 256, 32);

    // ---- LN stats from accumulators (exact fp32) ----
    {
        float s[16], s2[16];
#pragma unroll
        for (int mf = 0; mf < 4; mf++)
#pragma unroll
            for (int r = 0; r < 4; r++) {
                int i = mf * 4 + r;
                float v = 0.f, q = 0.f;
#pragma unroll
                for (int nt = 0; nt < 2; nt++) {
                    float a = acc[mf][nt][r];
                    v += a; q += a * a;
                }
                s[i] = v; s2[i] = q;
            }
#pragma unroll
        for (int m = 1; m <= 8; m <<= 1)
#pragma unroll
            for (int i = 0; i < 16; i++) {
                s[i]  += __shfl_xor(s[i], m);
                s2[i] += __shfl_xor(s2[i], m);
            }
#pragma unroll
        for (int i = 0; i < 16; i++)
            if (l16 == i) {
                int row = (i >> 2) * 16 + quad * 4 + (i & 3);
                psum[row * 9 + wave] = s[i];
                psq[row * 9 + wave]  = s2[i];
            }
    }
    __syncthreads();
    if (tid < 64) {
        float ss = 0.f, qq = 0.f;
#pragma unroll
        for (int p = 0; p < 8; p++) { ss += psum[tid * 9 + p]; qq += psq[tid * 9 + p]; }
        float mu = ss * 0.00390625f;
        float var = fmaxf(qq * 0.00390625f - mu * mu, 0.f);
        muA[tid] = mu;
        rsA[tid] = rsqrtf(var + 1e-5f);
    }
    __syncthreads();

    // ---- normalize acc -> normed bf16 [64][264] (aliases As) ----
#pragma unroll
    for (int nt = 0; nt < 2; nt++) {
        int col = nsl + nt * 16 + l16;
        float g = gmm[col], bt = bta[col];
#pragma unroll
        for (int mf = 0; mf < 4; mf++)
#pragma unroll
            for (int r = 0; r < 4; r++) {
                int row = mf * 16 + quad * 4 + r;
                normed[row * 264 + col] =
                    f2bf((acc[mf][nt][r] - muA[row]) * rsA[row] * g + bt);
            }
    }
    __syncthreads();

    // ---- out = normed @ out_W + out_b (B pre-staged in BA/BB) ----
    floatx4 acc2[4][2];
#pragma unroll
    for (int i = 0; i < 4; i++)
#pragma unroll
        for (int j = 0; j < 2; j++) acc2[i][j] = {0.f, 0.f, 0.f, 0.f};
    gemm_pre<4>(normed, 264, BA, acc2, l16, quad);        // k 0..127
    gemm_pre<4>(normed + 128, 264, BB, acc2, l16, quad);  // k 128..255

    float* op = out + (size_t)m0 * 256;
#pragma unroll
    for (int nt = 0; nt < 2; nt++) {
        int col = nsl + nt * 16 + l16;
        float ob = outb[col];
#pragma unroll
        for (int mf = 0; mf < 4; mf++)
#pragma unroll
            for (int r = 0; r < 4; r++) {
                int row = mf * 16 + quad * 4 + r;
                op[row * 256 + col] = acc2[mf][nt][r] + ob;
            }
    }
}

// -------------------------------------------------------------- launch ----
extern "C" void kernel_launch(void* const* d_in, const int* in_sizes, int n_in,
                              void* d_out, int out_size, void* d_ws, size_t ws_size,
                              hipStream_t stream)
{
    (void)in_sizes; (void)n_in; (void)out_size; (void)ws_size;
    const float* x     = (const float*)d_in[0];
    const float* ck5   = (const float*)d_in[1];
    const float* ck9   = (const float*)d_in[2];
    const float* ck17  = (const float*)d_in[3];
    const float* projW = (const float*)d_in[4];
    const float* projb = (const float*)d_in[5];
    const float* rW    = (const float*)d_in[6];
    const float* rb    = (const float*)d_in[7];
    const float* outW  = (const float*)d_in[8];
    const float* outb  = (const float*)d_in[9];
    const float* gmm   = (const float*)d_in[10];
    const float* bta   = (const float*)d_in[11];

    __hip_bfloat16* projWT = (__hip_bfloat16*)d_ws;
    __hip_bfloat16* outWT  = (__hip_bfloat16*)((char*)d_ws + 1572864);
    __hip_bfloat16* projbT = (__hip_bfloat16*)((char*)d_ws + 1703936);
    __hip_bfloat16* rWT    = (__hip_bfloat16*)((char*)d_ws + 1720320);

    prep_kernel<<<dim3(209), dim3(256), 0, stream>>>(
        rW, projW, outW, projb, projWT, outWT, projbT, rWT);
    fused_kernel<<<dim3(256), dim3(512), 0, stream>>>(
        x, ck5, ck9, ck17, rb, gmm, bta, outb,
        projWT, outWT, projbT, rWT, (float*)d_out);
}